// Round 1
// baseline (246.593 us; speedup 1.0000x reference)
//
#include <hip/hip_runtime.h>

#define NB 16
#define NC 8
#define NH 512
#define NW 512
#define HW (NH*NW)
#define NSEG 17
#define BPS 128                       // blocks per sample
#define PIX_PER_BLOCK (HW / BPS)      // 2048
#define LGG 3.0f

__global__ __launch_bounds__(256) void init_ws(float* ws, int n) {
    int i = blockIdx.x * 256 + threadIdx.x;
    if (i < n) ws[i] = 0.f;   // zero bit-pattern also valid for the uint arrays
}

__global__ __launch_bounds__(256) void accum(
    const int* __restrict__ gk, const int* __restrict__ mask,
    const float* __restrict__ sim,
    float* __restrict__ g_sums, unsigned* __restrict__ g_cnt,
    unsigned* __restrict__ g_mcnt)
{
    __shared__ float    s_sums[4][NSEG][NC];   // per-wave replicas
    __shared__ unsigned s_cm[4][NSEG];         // low16 = count, high16 = masked count

    const int tid = threadIdx.x;
    const int wid = tid >> 6;
    const int b   = blockIdx.x / BPS;
    const int blk = blockIdx.x % BPS;

    for (int i = tid; i < 4*NSEG*NC; i += 256) ((float*)s_sums)[i] = 0.f;
    for (int i = tid; i < 4*NSEG;    i += 256) ((unsigned*)s_cm)[i] = 0u;
    __syncthreads();

    const int*   gkb = gk   + (size_t)b * HW;
    const int*   mb  = mask + (size_t)b * HW;
    const float* sb  = sim  + (size_t)b * NC * HW;
    const int base = blk * PIX_PER_BLOCK;

    #pragma unroll
    for (int it = 0; it < PIX_PER_BLOCK / (256*4); ++it) {
        const int hw0 = base + (it*256 + tid) * 4;
        const int4 g4 = *(const int4*)(gkb + hw0);
        const int4 m4 = *(const int4*)(mb  + hw0);
        float4 v[NC];
        #pragma unroll
        for (int c = 0; c < NC; ++c)
            v[c] = *(const float4*)(sb + (size_t)c*HW + hw0);

        const int gs[4] = {g4.x, g4.y, g4.z, g4.w};
        const int ms[4] = {m4.x, m4.y, m4.z, m4.w};
        #pragma unroll
        for (int p = 0; p < 4; ++p) {
            const int t = gs[p];
            atomicAdd(&s_cm[wid][t], 1u + (((unsigned)ms[p]) << 16));
            #pragma unroll
            for (int c = 0; c < NC; ++c)
                atomicAdd(&s_sums[wid][t][c], (&v[c].x)[p]);
        }
    }
    __syncthreads();

    // flush block partials to per-sample global accumulators
    if (tid < NSEG*NC) {
        const int t = tid / NC, c = tid % NC;
        const float s = s_sums[0][t][c] + s_sums[1][t][c]
                      + s_sums[2][t][c] + s_sums[3][t][c];
        atomicAdd(&g_sums[(b*NSEG + t)*NC + c], s);
    } else if (tid < NSEG*NC + NSEG) {
        const int t = tid - NSEG*NC;
        const unsigned pk = s_cm[0][t] + s_cm[1][t] + s_cm[2][t] + s_cm[3][t];
        atomicAdd(&g_cnt[b*NSEG + t],  pk & 0xFFFFu);
        atomicAdd(&g_mcnt[b*NSEG + t], pk >> 16);
    }
}

__global__ __launch_bounds__(256) void finalize(
    const float* __restrict__ g_sums, const unsigned* __restrict__ g_cnt,
    const unsigned* __restrict__ g_mcnt, float* __restrict__ out)
{
    __shared__ float    means[NSEG][NC];
    __shared__ int      present[NSEG];
    __shared__ float    s_loss;
    __shared__ unsigned s_n;
    __shared__ float    tl, tv;
    const int tid = threadIdx.x;
    if (tid == 0) { tl = 0.f; tv = 0.f; }

    for (int b = 0; b < NB; ++b) {
        __syncthreads();
        if (tid < NSEG*NC) {
            const int t = tid / NC, c = tid % NC;
            const float cnt = (float)g_cnt[b*NSEG + t];
            means[t][c] = g_sums[(b*NSEG + t)*NC + c] / fmaxf(cnt, 1.f);
        }
        if (tid < NSEG) present[tid] = (tid != 0) && (g_mcnt[b*NSEG + tid] > 0);
        if (tid == 0) { s_loss = 0.f; s_n = 0u; }
        __syncthreads();

        for (int p = tid; p < NSEG*NSEG; p += 256) {
            const int i = p / NSEG, j = p % NSEG;
            if (i != j && present[i] && present[j]) {
                float d2 = 0.f;
                #pragma unroll
                for (int c = 0; c < NC; ++c) {
                    const float d = means[i][c] - means[j][c];
                    d2 += d * d;
                }
                const float dist = sqrtf(d2 + 1e-12f);
                const float r = fmaxf(LGG - dist, 0.f);
                atomicAdd(&s_loss, logf(r*r + 1.f));
                atomicAdd(&s_n, 1u);
            }
        }
        __syncthreads();
        if (tid == 0) {
            int np = 0;
            for (int t = 0; t < NSEG; ++t) np += present[t];
            const float sv = (np >= 2) ? 1.f : 0.f;
            tl += sv * (s_loss / fmaxf((float)s_n, 1.f));
            tv += sv;
        }
    }
    __syncthreads();
    if (tid == 0) out[0] = (tv > 0.f) ? tl / fmaxf(tv, 1.f) : 0.f;
}

extern "C" void kernel_launch(void* const* d_in, const int* in_sizes, int n_in,
                              void* d_out, int out_size, void* d_ws, size_t ws_size,
                              hipStream_t stream) {
    const int*   gk   = (const int*)d_in[0];
    const int*   mask = (const int*)d_in[1];
    const float* sim  = (const float*)d_in[2];
    float* out = (float*)d_out;

    float*    g_sums = (float*)d_ws;                 // NB*NSEG*NC floats
    unsigned* g_cnt  = (unsigned*)(g_sums + NB*NSEG*NC);  // NB*NSEG
    unsigned* g_mcnt = g_cnt + NB*NSEG;                   // NB*NSEG

    const int nws = NB*NSEG*NC + 2*NB*NSEG;
    init_ws<<<(nws + 255)/256, 256, 0, stream>>>((float*)d_ws, nws);
    accum<<<NB*BPS, 256, 0, stream>>>(gk, mask, sim, g_sums, g_cnt, g_mcnt);
    finalize<<<1, 256, 0, stream>>>(g_sums, g_cnt, g_mcnt, out);
}

// Round 2
// 127.328 us; speedup vs baseline: 1.9367x; 1.9367x over previous
//
#include <hip/hip_runtime.h>

#define NB 16
#define NC 8
#define HW (512*512)
#define NT 16                         // tags 1..16 (tag 0 never participates)
#define BPS 32                        // blocks per sample
#define THREADS 256
#define ITERS (HW / (BPS * THREADS * 4))   // 8 iterations of 4 pixels/thread
#define LGG 3.0f

// ws layout: g_sums [NB][NT][NC] f32 | g_cnt [NB][NT] f32 | g_pb [NB] u32

__global__ __launch_bounds__(256) void init_ws(float* ws) {
    const int n = NB*NT*NC + NB*NT + NB;
    const int i = blockIdx.x * 256 + threadIdx.x;
    if (i < n) ws[i] = 0.f;
}

__global__ __launch_bounds__(THREADS, 2) void accum(
    const int* __restrict__ gk, const int* __restrict__ mask,
    const float* __restrict__ sim,
    float* __restrict__ g_sums, float* __restrict__ g_cnt,
    unsigned* __restrict__ g_pb)
{
    const int tid = threadIdx.x;
    const int b   = blockIdx.x / BPS;
    const int blk = blockIdx.x % BPS;
    const int base = blk * (HW / BPS);

    const int*   gkb = gk   + (size_t)b * HW;
    const int*   mb  = mask + (size_t)b * HW;
    const float* sb  = sim  + (size_t)b * NC * HW;

    float s[NT][NC];
    float cnt[NT];
    unsigned pb = 0u;
    #pragma unroll
    for (int t = 0; t < NT; ++t) {
        cnt[t] = 0.f;
        #pragma unroll
        for (int c = 0; c < NC; ++c) s[t][c] = 0.f;
    }

    #pragma unroll 2
    for (int it = 0; it < ITERS; ++it) {
        const int hw0 = base + (it*THREADS + tid) * 4;
        const int4 g4 = *(const int4*)(gkb + hw0);
        const int4 m4 = *(const int4*)(mb  + hw0);
        float4 v[NC];
        #pragma unroll
        for (int c = 0; c < NC; ++c)
            v[c] = *(const float4*)(sb + (size_t)c*HW + hw0);

        const int gs[4] = {g4.x, g4.y, g4.z, g4.w};
        const int ms[4] = {m4.x, m4.y, m4.z, m4.w};
        #pragma unroll
        for (int p = 0; p < 4; ++p) {
            const int g = gs[p];
            pb |= ms[p] ? (1u << g) : 0u;
            #pragma unroll
            for (int t = 0; t < NT; ++t) {
                const float oh = (g == t+1) ? 1.f : 0.f;
                cnt[t] += oh;
                #pragma unroll
                for (int c = 0; c < NC; ++c)
                    s[t][c] = fmaf(oh, (&v[c].x)[p], s[t][c]);
            }
        }
    }

    // ---- block reduction: wave shuffle-reduce, then cross-wave via LDS ----
    __shared__ float    lred[4][NT*NC + NT];
    __shared__ unsigned lpb[4];
    const int wid = tid >> 6, lane = tid & 63;

    #pragma unroll
    for (int t = 0; t < NT; ++t) {
        #pragma unroll
        for (int c = 0; c < NC; ++c) {
            float x = s[t][c];
            #pragma unroll
            for (int o = 32; o; o >>= 1) x += __shfl_xor(x, o);
            if (lane == 0) lred[wid][t*NC + c] = x;
        }
        float x = cnt[t];
        #pragma unroll
        for (int o = 32; o; o >>= 1) x += __shfl_xor(x, o);
        if (lane == 0) lred[wid][NT*NC + t] = x;
    }
    {
        unsigned u = pb;
        #pragma unroll
        for (int o = 32; o; o >>= 1) u |= __shfl_xor(u, o);
        if (lane == 0) lpb[wid] = u;
    }
    __syncthreads();

    for (int i = tid; i < NT*NC + NT; i += THREADS) {
        const float tot = lred[0][i] + lred[1][i] + lred[2][i] + lred[3][i];
        if (i < NT*NC) atomicAdd(&g_sums[b*NT*NC + i], tot);
        else           atomicAdd(&g_cnt[b*NT + (i - NT*NC)], tot);
    }
    if (tid == 0) atomicOr(&g_pb[b], lpb[0] | lpb[1] | lpb[2] | lpb[3]);
}

__global__ __launch_bounds__(256) void finalize(
    const float* __restrict__ g_sums, const float* __restrict__ g_cnt,
    const unsigned* __restrict__ g_pb, float* __restrict__ out)
{
    __shared__ float means[NB][NT][NC];
    __shared__ float sl[NB], sn[NB];
    const int tid = threadIdx.x;

    #pragma unroll
    for (int k = 0; k < (NB*NT*NC)/256; ++k) {    // 8
        const int idx = k*256 + tid;
        const int bb = idx >> 7;           // /(NT*NC)
        const int tt = (idx >> 3) & 15;
        const int cc = idx & 7;
        const float cv = g_cnt[bb*NT + tt];
        means[bb][tt][cc] = g_sums[idx] / fmaxf(cv, 1.f);
    }
    __syncthreads();

    const int b = tid >> 4, i = tid & 15;          // sample, tag-1
    const unsigned pres = g_pb[b] & 0x1FFFEu;      // exclude tag 0
    float loss = 0.f, nv = 0.f;
    if ((pres >> (i+1)) & 1u) {
        #pragma unroll
        for (int j = 0; j < NT; ++j) {
            if (j != i && ((pres >> (j+1)) & 1u)) {
                float d2 = 0.f;
                #pragma unroll
                for (int c = 0; c < NC; ++c) {
                    const float d = means[b][i][c] - means[b][j][c];
                    d2 += d * d;
                }
                const float dist = sqrtf(d2 + 1e-12f);
                const float r = fmaxf(LGG - dist, 0.f);
                loss += logf(r*r + 1.f);
                nv += 1.f;
            }
        }
    }
    #pragma unroll
    for (int o = 8; o; o >>= 1) { loss += __shfl_xor(loss, o); nv += __shfl_xor(nv, o); }
    if (i == 0) {
        const float v = (__popc(pres) >= 2) ? 1.f : 0.f;
        sl[b] = v * (loss / fmaxf(nv, 1.f));
        sn[b] = v;
    }
    __syncthreads();
    if (tid == 0) {
        float tl = 0.f, tv = 0.f;
        for (int bb = 0; bb < NB; ++bb) { tl += sl[bb]; tv += sn[bb]; }
        out[0] = (tv > 0.f) ? tl / tv : 0.f;
    }
}

extern "C" void kernel_launch(void* const* d_in, const int* in_sizes, int n_in,
                              void* d_out, int out_size, void* d_ws, size_t ws_size,
                              hipStream_t stream) {
    const int*   gk   = (const int*)d_in[0];
    const int*   mask = (const int*)d_in[1];
    const float* sim  = (const float*)d_in[2];
    float* out = (float*)d_out;

    float*    g_sums = (float*)d_ws;                       // NB*NT*NC
    float*    g_cnt  = g_sums + NB*NT*NC;                  // NB*NT
    unsigned* g_pb   = (unsigned*)(g_cnt + NB*NT);         // NB

    const int nws = NB*NT*NC + NB*NT + NB;
    init_ws<<<(nws + 255)/256, 256, 0, stream>>>((float*)d_ws);
    accum<<<NB*BPS, THREADS, 0, stream>>>(gk, mask, sim, g_sums, g_cnt, g_pb);
    finalize<<<1, 256, 0, stream>>>(g_sums, g_cnt, g_pb, out);
}

// Round 3
// 112.253 us; speedup vs baseline: 2.1968x; 1.1343x over previous
//
#include <hip/hip_runtime.h>

#define NB 16
#define NC 8
#define HC 4                          // channels per half-pass
#define HW (512*512)
#define NT 16                         // tags 1..16 (tag 0 never participates)
#define BPS 32                        // blocks per sample
#define THREADS 256
#define ITERS (HW / (BPS * THREADS * 4))   // 8 iterations of 4 pixels/thread
#define LGG 3.0f

// ws layout: g_sums [NB][NT][NC] f32 | g_cnt [NB][NT] f32 | g_pb [NB] u32

__global__ __launch_bounds__(256) void init_ws(float* ws) {
    const int n = NB*NT*NC + NB*NT + NB;
    const int i = blockIdx.x * 256 + threadIdx.x;
    if (i < n) ws[i] = 0.f;
}

// HALF=0: channels 0..3 + counts + presence bitmask. HALF=1: channels 4..7 only.
template<int HALF>
__global__ __launch_bounds__(THREADS, 4) void accum(
    const int* __restrict__ gk, const int* __restrict__ mask,
    const float* __restrict__ sim,
    float* __restrict__ g_sums, float* __restrict__ g_cnt,
    unsigned* __restrict__ g_pb)
{
    const int tid = threadIdx.x;
    const int b   = blockIdx.x / BPS;
    const int blk = blockIdx.x % BPS;
    const int base = blk * (HW / BPS);

    const int*   gkb = gk   + (size_t)b * HW;
    const int*   mb  = mask + (size_t)b * HW;
    const float* sb  = sim  + (size_t)b * NC * HW + (size_t)HALF * HC * HW;

    float s[NT][HC];
    float cnt[NT];
    unsigned pb = 0u;
    #pragma unroll
    for (int t = 0; t < NT; ++t) {
        cnt[t] = 0.f;
        #pragma unroll
        for (int c = 0; c < HC; ++c) s[t][c] = 0.f;
    }

    for (int it = 0; it < ITERS; ++it) {
        const int hw0 = base + (it*THREADS + tid) * 4;
        const int4 g4 = *(const int4*)(gkb + hw0);
        int4 m4 = make_int4(0,0,0,0);
        if (HALF == 0) m4 = *(const int4*)(mb + hw0);
        float4 v[HC];
        #pragma unroll
        for (int c = 0; c < HC; ++c)
            v[c] = *(const float4*)(sb + (size_t)c*HW + hw0);

        const int gs[4] = {g4.x, g4.y, g4.z, g4.w};
        const int ms[4] = {m4.x, m4.y, m4.z, m4.w};
        #pragma unroll
        for (int p = 0; p < 4; ++p) {
            const int g = gs[p];
            if (HALF == 0) pb |= ms[p] ? (1u << g) : 0u;
            #pragma unroll
            for (int t = 0; t < NT; ++t) {
                const float oh = (g == t+1) ? 1.f : 0.f;
                if (HALF == 0) cnt[t] += oh;
                #pragma unroll
                for (int c = 0; c < HC; ++c)
                    s[t][c] = fmaf(oh, (&v[c].x)[p], s[t][c]);
            }
        }
    }

    // ---- block reduction: wave shuffle-reduce, then cross-wave via LDS ----
    __shared__ float    lred[4][NT*HC + NT];
    __shared__ unsigned lpb[4];
    const int wid = tid >> 6, lane = tid & 63;

    #pragma unroll
    for (int t = 0; t < NT; ++t) {
        #pragma unroll
        for (int c = 0; c < HC; ++c) {
            float x = s[t][c];
            #pragma unroll
            for (int o = 32; o; o >>= 1) x += __shfl_xor(x, o);
            if (lane == 0) lred[wid][t*HC + c] = x;
        }
        if (HALF == 0) {
            float x = cnt[t];
            #pragma unroll
            for (int o = 32; o; o >>= 1) x += __shfl_xor(x, o);
            if (lane == 0) lred[wid][NT*HC + t] = x;
        }
    }
    if (HALF == 0) {
        unsigned u = pb;
        #pragma unroll
        for (int o = 32; o; o >>= 1) u |= __shfl_xor(u, o);
        if (lane == 0) lpb[wid] = u;
    }
    __syncthreads();

    const int nred = HALF == 0 ? NT*HC + NT : NT*HC;
    for (int i = tid; i < nred; i += THREADS) {
        const float tot = lred[0][i] + lred[1][i] + lred[2][i] + lred[3][i];
        if (i < NT*HC) {
            const int t = i / HC, c = i % HC;
            atomicAdd(&g_sums[(b*NT + t)*NC + HALF*HC + c], tot);
        } else {
            atomicAdd(&g_cnt[b*NT + (i - NT*HC)], tot);
        }
    }
    if (HALF == 0 && tid == 0) atomicOr(&g_pb[b], lpb[0] | lpb[1] | lpb[2] | lpb[3]);
}

__global__ __launch_bounds__(256) void finalize(
    const float* __restrict__ g_sums, const float* __restrict__ g_cnt,
    const unsigned* __restrict__ g_pb, float* __restrict__ out)
{
    __shared__ float means[NB][NT][NC];
    __shared__ float sl[NB], sn[NB];
    const int tid = threadIdx.x;

    #pragma unroll
    for (int k = 0; k < (NB*NT*NC)/256; ++k) {    // 8
        const int idx = k*256 + tid;
        const int bb = idx >> 7;           // /(NT*NC)
        const int tt = (idx >> 3) & 15;
        const int cc = idx & 7;
        const float cv = g_cnt[bb*NT + tt];
        means[bb][tt][cc] = g_sums[idx] / fmaxf(cv, 1.f);
    }
    __syncthreads();

    const int b = tid >> 4, i = tid & 15;          // sample, tag-1
    const unsigned pres = g_pb[b] & 0x1FFFEu;      // exclude tag 0
    float loss = 0.f, nv = 0.f;
    if ((pres >> (i+1)) & 1u) {
        #pragma unroll
        for (int j = 0; j < NT; ++j) {
            if (j != i && ((pres >> (j+1)) & 1u)) {
                float d2 = 0.f;
                #pragma unroll
                for (int c = 0; c < NC; ++c) {
                    const float d = means[b][i][c] - means[b][j][c];
                    d2 += d * d;
                }
                const float dist = sqrtf(d2 + 1e-12f);
                const float r = fmaxf(LGG - dist, 0.f);
                loss += logf(r*r + 1.f);
                nv += 1.f;
            }
        }
    }
    #pragma unroll
    for (int o = 8; o; o >>= 1) { loss += __shfl_xor(loss, o); nv += __shfl_xor(nv, o); }
    if (i == 0) {
        const float v = (__popc(pres) >= 2) ? 1.f : 0.f;
        sl[b] = v * (loss / fmaxf(nv, 1.f));
        sn[b] = v;
    }
    __syncthreads();
    if (tid == 0) {
        float tl = 0.f, tv = 0.f;
        for (int bb = 0; bb < NB; ++bb) { tl += sl[bb]; tv += sn[bb]; }
        out[0] = (tv > 0.f) ? tl / tv : 0.f;
    }
}

extern "C" void kernel_launch(void* const* d_in, const int* in_sizes, int n_in,
                              void* d_out, int out_size, void* d_ws, size_t ws_size,
                              hipStream_t stream) {
    const int*   gk   = (const int*)d_in[0];
    const int*   mask = (const int*)d_in[1];
    const float* sim  = (const float*)d_in[2];
    float* out = (float*)d_out;

    float*    g_sums = (float*)d_ws;                       // NB*NT*NC
    float*    g_cnt  = g_sums + NB*NT*NC;                  // NB*NT
    unsigned* g_pb   = (unsigned*)(g_cnt + NB*NT);         // NB

    const int nws = NB*NT*NC + NB*NT + NB;
    init_ws<<<(nws + 255)/256, 256, 0, stream>>>((float*)d_ws);
    accum<0><<<NB*BPS, THREADS, 0, stream>>>(gk, mask, sim, g_sums, g_cnt, g_pb);
    accum<1><<<NB*BPS, THREADS, 0, stream>>>(gk, mask, sim, g_sums, g_cnt, g_pb);
    finalize<<<1, 256, 0, stream>>>(g_sums, g_cnt, g_pb, out);
}

// Round 4
// 88.656 us; speedup vs baseline: 2.7814x; 1.2662x over previous
//
#include <hip/hip_runtime.h>

#define NB 16
#define NC 8
#define HC 4                          // channels per half-pass
#define HW (512*512)
#define NT 16                         // tags 1..16 (tag 0 never participates)
#define BPS 32                        // blocks per sample
#define THREADS 256
#define ITERS (HW / (BPS * THREADS * 4))   // 8 iterations of 4 pixels/thread
#define LGG 3.0f

// ws layout: g_sums [NB][NT][NC] f32 | g_cnt [NB][NT] f32 | g_pb [NB] u32

__global__ __launch_bounds__(256) void init_ws(float* ws) {
    const int n = NB*NT*NC + NB*NT + NB;
    const int i = blockIdx.x * 256 + threadIdx.x;
    if (i < n) ws[i] = 0.f;
}

// HALF=0: channels 0..3 + counts + presence bitmask. HALF=1: channels 4..7 only.
// amdgpu_waves_per_eu(4,4): pin allocator to exactly 4 waves/EU -> 128-VGPR
// budget. launch_bounds min-waves alone lets the heuristic pick 8/EU (64 VGPR)
// and spill the accumulator array (R2/R3: 154 MB scratch writes).
template<int HALF>
__global__ __attribute__((amdgpu_waves_per_eu(4, 4)))
__launch_bounds__(THREADS) void accum(
    const int* __restrict__ gk, const int* __restrict__ mask,
    const float* __restrict__ sim,
    float* __restrict__ g_sums, float* __restrict__ g_cnt,
    unsigned* __restrict__ g_pb)
{
    const int tid = threadIdx.x;
    const int b   = blockIdx.x / BPS;
    const int blk = blockIdx.x % BPS;
    const int base = blk * (HW / BPS);

    const int*   gkb = gk   + (size_t)b * HW;
    const int*   mb  = mask + (size_t)b * HW;
    const float* sb  = sim  + (size_t)b * NC * HW + (size_t)HALF * HC * HW;

    float s[NT][HC];
    float cnt[NT];
    unsigned pb = 0u;
    #pragma unroll
    for (int t = 0; t < NT; ++t) {
        cnt[t] = 0.f;
        #pragma unroll
        for (int c = 0; c < HC; ++c) s[t][c] = 0.f;
    }

    #pragma unroll 1
    for (int it = 0; it < ITERS; ++it) {
        const int hw0 = base + (it*THREADS + tid) * 4;
        const int4 g4 = *(const int4*)(gkb + hw0);
        int4 m4 = make_int4(0,0,0,0);
        if (HALF == 0) m4 = *(const int4*)(mb + hw0);
        float4 v[HC];
        #pragma unroll
        for (int c = 0; c < HC; ++c)
            v[c] = *(const float4*)(sb + (size_t)c*HW + hw0);

        const int gs[4] = {g4.x, g4.y, g4.z, g4.w};
        const int ms[4] = {m4.x, m4.y, m4.z, m4.w};
        #pragma unroll
        for (int p = 0; p < 4; ++p) {
            const int g = gs[p];
            if (HALF == 0) pb |= ms[p] ? (1u << g) : 0u;
            #pragma unroll
            for (int t = 0; t < NT; ++t) {
                const float oh = (g == t+1) ? 1.f : 0.f;
                if (HALF == 0) cnt[t] += oh;
                #pragma unroll
                for (int c = 0; c < HC; ++c)
                    s[t][c] = fmaf(oh, (&v[c].x)[p], s[t][c]);
            }
        }
    }

    // ---- block reduction: wave shuffle-reduce, then cross-wave via LDS ----
    __shared__ float    lred[4][NT*HC + NT];
    __shared__ unsigned lpb[4];
    const int wid = tid >> 6, lane = tid & 63;

    #pragma unroll
    for (int t = 0; t < NT; ++t) {
        #pragma unroll
        for (int c = 0; c < HC; ++c) {
            float x = s[t][c];
            #pragma unroll
            for (int o = 32; o; o >>= 1) x += __shfl_xor(x, o);
            if (lane == 0) lred[wid][t*HC + c] = x;
        }
        if (HALF == 0) {
            float x = cnt[t];
            #pragma unroll
            for (int o = 32; o; o >>= 1) x += __shfl_xor(x, o);
            if (lane == 0) lred[wid][NT*HC + t] = x;
        }
    }
    if (HALF == 0) {
        unsigned u = pb;
        #pragma unroll
        for (int o = 32; o; o >>= 1) u |= __shfl_xor(u, o);
        if (lane == 0) lpb[wid] = u;
    }
    __syncthreads();

    const int nred = HALF == 0 ? NT*HC + NT : NT*HC;
    for (int i = tid; i < nred; i += THREADS) {
        const float tot = lred[0][i] + lred[1][i] + lred[2][i] + lred[3][i];
        if (i < NT*HC) {
            const int t = i / HC, c = i % HC;
            atomicAdd(&g_sums[(b*NT + t)*NC + HALF*HC + c], tot);
        } else {
            atomicAdd(&g_cnt[b*NT + (i - NT*HC)], tot);
        }
    }
    if (HALF == 0 && tid == 0) atomicOr(&g_pb[b], lpb[0] | lpb[1] | lpb[2] | lpb[3]);
}

__global__ __launch_bounds__(256) void finalize(
    const float* __restrict__ g_sums, const float* __restrict__ g_cnt,
    const unsigned* __restrict__ g_pb, float* __restrict__ out)
{
    __shared__ float means[NB][NT][NC];
    __shared__ float sl[NB], sn[NB];
    const int tid = threadIdx.x;

    #pragma unroll
    for (int k = 0; k < (NB*NT*NC)/256; ++k) {    // 8
        const int idx = k*256 + tid;
        const int bb = idx >> 7;           // /(NT*NC)
        const int tt = (idx >> 3) & 15;
        const int cc = idx & 7;
        const float cv = g_cnt[bb*NT + tt];
        means[bb][tt][cc] = g_sums[idx] / fmaxf(cv, 1.f);
    }
    __syncthreads();

    const int b = tid >> 4, i = tid & 15;          // sample, tag-1
    const unsigned pres = g_pb[b] & 0x1FFFEu;      // exclude tag 0
    float loss = 0.f, nv = 0.f;
    if ((pres >> (i+1)) & 1u) {
        #pragma unroll
        for (int j = 0; j < NT; ++j) {
            if (j != i && ((pres >> (j+1)) & 1u)) {
                float d2 = 0.f;
                #pragma unroll
                for (int c = 0; c < NC; ++c) {
                    const float d = means[b][i][c] - means[b][j][c];
                    d2 += d * d;
                }
                const float dist = sqrtf(d2 + 1e-12f);
                const float r = fmaxf(LGG - dist, 0.f);
                loss += logf(r*r + 1.f);
                nv += 1.f;
            }
        }
    }
    #pragma unroll
    for (int o = 8; o; o >>= 1) { loss += __shfl_xor(loss, o); nv += __shfl_xor(nv, o); }
    if (i == 0) {
        const float v = (__popc(pres) >= 2) ? 1.f : 0.f;
        sl[b] = v * (loss / fmaxf(nv, 1.f));
        sn[b] = v;
    }
    __syncthreads();
    if (tid == 0) {
        float tl = 0.f, tv = 0.f;
        for (int bb = 0; bb < NB; ++bb) { tl += sl[bb]; tv += sn[bb]; }
        out[0] = (tv > 0.f) ? tl / tv : 0.f;
    }
}

extern "C" void kernel_launch(void* const* d_in, const int* in_sizes, int n_in,
                              void* d_out, int out_size, void* d_ws, size_t ws_size,
                              hipStream_t stream) {
    const int*   gk   = (const int*)d_in[0];
    const int*   mask = (const int*)d_in[1];
    const float* sim  = (const float*)d_in[2];
    float* out = (float*)d_out;

    float*    g_sums = (float*)d_ws;                       // NB*NT*NC
    float*    g_cnt  = g_sums + NB*NT*NC;                  // NB*NT
    unsigned* g_pb   = (unsigned*)(g_cnt + NB*NT);         // NB

    const int nws = NB*NT*NC + NB*NT + NB;
    init_ws<<<(nws + 255)/256, 256, 0, stream>>>((float*)d_ws);
    accum<0><<<NB*BPS, THREADS, 0, stream>>>(gk, mask, sim, g_sums, g_cnt, g_pb);
    accum<1><<<NB*BPS, THREADS, 0, stream>>>(gk, mask, sim, g_sums, g_cnt, g_pb);
    finalize<<<1, 256, 0, stream>>>(g_sums, g_cnt, g_pb, out);
}

// Round 5
// 57.342 us; speedup vs baseline: 4.3004x; 1.5461x over previous
//
#include <hip/hip_runtime.h>

#define NB 16
#define NC 8
#define HW (512*512)
#define NT 16                          // tags 1..16 (tag 0 never participates)
#define BPS 32                         // block-slices per sample
#define THREADS 256
#define PIXB (HW / BPS)                // 8192 pixels per slice
#define ITERS (PIXB / (THREADS*4))     // 8 iters of 4 px/thread
#define NQ 5                           // 4 sim channel-pair quarters + 1 count flavor
#define LGG 3.0f

// ws layout: g_sums [NB][NT][NC] f32 | g_cnt [NB][NT] f32 | g_pb [NB] u32

__global__ __launch_bounds__(256) void init_ws(float* ws) {
    const int n = NB*NT*NC + NB*NT + NB;
    const int i = blockIdx.x * 256 + threadIdx.x;
    if (i < n) ws[i] = 0.f;
}

// One kernel, 5 block flavors (q = blockIdx.x % 5):
//   q in 0..3 : accumulate channels {2q, 2q+1} into 32 f32 regs (no mask read)
//   q == 4    : counts (16 u32 regs) + presence bitmask (reads gk + mask only)
// Worst-case live set ~56 VGPR -> fits the allocator's default 8-waves/EU
// 64-VGPR budget with NO spill (R2-R4 all spilled fighting this).
__global__ __launch_bounds__(THREADS) void accum(
    const int* __restrict__ gk, const int* __restrict__ mask,
    const float* __restrict__ sim,
    float* __restrict__ g_sums, float* __restrict__ g_cnt,
    unsigned* __restrict__ g_pb)
{
    const int tid = threadIdx.x;
    const int q   = blockIdx.x % NQ;
    const int bb  = blockIdx.x / NQ;
    const int b   = bb / BPS;
    const int blk = bb % BPS;
    const int base = blk * PIXB;
    const int* gkb = gk + (size_t)b * HW + base;

    __shared__ float    lred[4][2*NT];
    __shared__ unsigned lpb[4];
    const int wid = tid >> 6, lane = tid & 63;

    if (q < 4) {
        const float* sb = sim + (size_t)b*NC*HW + (size_t)(q*2)*HW + base;
        float s0[NT], s1[NT];
        #pragma unroll
        for (int t = 0; t < NT; ++t) { s0[t] = 0.f; s1[t] = 0.f; }

        #pragma unroll 1
        for (int it = 0; it < ITERS; ++it) {
            const int off = (it*THREADS + tid) * 4;
            const int4   g4 = *(const int4*)(gkb + off);
            const float4 v0 = *(const float4*)(sb + off);
            const float4 v1 = *(const float4*)(sb + HW + off);
            const int   gs[4] = {g4.x, g4.y, g4.z, g4.w};
            const float a0[4] = {v0.x, v0.y, v0.z, v0.w};
            const float a1[4] = {v1.x, v1.y, v1.z, v1.w};
            #pragma unroll
            for (int p = 0; p < 4; ++p) {
                const int g = gs[p];
                #pragma unroll
                for (int t = 0; t < NT; ++t) {
                    const float oh = (g == t+1) ? 1.f : 0.f;
                    s0[t] = fmaf(oh, a0[p], s0[t]);
                    s1[t] = fmaf(oh, a1[p], s1[t]);
                }
            }
        }

        #pragma unroll
        for (int t = 0; t < NT; ++t) {
            float x = s0[t], y = s1[t];
            #pragma unroll
            for (int o = 32; o; o >>= 1) { x += __shfl_xor(x, o); y += __shfl_xor(y, o); }
            if (lane == 0) { lred[wid][t] = x; lred[wid][NT + t] = y; }
        }
        __syncthreads();
        if (tid < 2*NT) {
            const float tot = lred[0][tid] + lred[1][tid] + lred[2][tid] + lred[3][tid];
            const int t = tid & 15, c = q*2 + (tid >> 4);
            atomicAdd(&g_sums[(b*NT + t)*NC + c], tot);
        }
    } else {
        const int* mb = mask + (size_t)b * HW + base;
        unsigned cnt[NT];
        unsigned pb = 0u;
        #pragma unroll
        for (int t = 0; t < NT; ++t) cnt[t] = 0u;

        #pragma unroll 1
        for (int it = 0; it < ITERS; ++it) {
            const int off = (it*THREADS + tid) * 4;
            const int4 g4 = *(const int4*)(gkb + off);
            const int4 m4 = *(const int4*)(mb  + off);
            const int gs[4] = {g4.x, g4.y, g4.z, g4.w};
            const int ms[4] = {m4.x, m4.y, m4.z, m4.w};
            #pragma unroll
            for (int p = 0; p < 4; ++p) {
                const int g = gs[p];
                pb |= ms[p] ? (1u << g) : 0u;
                #pragma unroll
                for (int t = 0; t < NT; ++t) cnt[t] += (g == t+1) ? 1u : 0u;
            }
        }

        #pragma unroll
        for (int t = 0; t < NT; ++t) {
            unsigned x = cnt[t];
            #pragma unroll
            for (int o = 32; o; o >>= 1) x += __shfl_xor(x, o);
            if (lane == 0) lred[wid][t] = (float)x;
        }
        {
            unsigned u = pb;
            #pragma unroll
            for (int o = 32; o; o >>= 1) u |= __shfl_xor(u, o);
            if (lane == 0) lpb[wid] = u;
        }
        __syncthreads();
        if (tid < NT) {
            const float tot = lred[0][tid] + lred[1][tid] + lred[2][tid] + lred[3][tid];
            atomicAdd(&g_cnt[b*NT + tid], tot);
        }
        if (tid == 0) atomicOr(&g_pb[b], lpb[0] | lpb[1] | lpb[2] | lpb[3]);
    }
}

__global__ __launch_bounds__(256) void finalize(
    const float* __restrict__ g_sums, const float* __restrict__ g_cnt,
    const unsigned* __restrict__ g_pb, float* __restrict__ out)
{
    __shared__ float means[NB][NT][NC];
    __shared__ float sl[NB], sn[NB];
    const int tid = threadIdx.x;

    #pragma unroll
    for (int k = 0; k < (NB*NT*NC)/256; ++k) {    // 8
        const int idx = k*256 + tid;
        const int bb = idx >> 7;
        const int tt = (idx >> 3) & 15;
        const int cc = idx & 7;
        const float cv = g_cnt[bb*NT + tt];
        means[bb][tt][cc] = g_sums[idx] / fmaxf(cv, 1.f);
    }
    __syncthreads();

    const int b = tid >> 4, i = tid & 15;          // sample, tag-1
    const unsigned pres = g_pb[b] & 0x1FFFEu;      // exclude tag 0
    float loss = 0.f, nv = 0.f;
    if ((pres >> (i+1)) & 1u) {
        #pragma unroll
        for (int j = 0; j < NT; ++j) {
            if (j != i && ((pres >> (j+1)) & 1u)) {
                float d2 = 0.f;
                #pragma unroll
                for (int c = 0; c < NC; ++c) {
                    const float d = means[b][i][c] - means[b][j][c];
                    d2 += d * d;
                }
                const float dist = sqrtf(d2 + 1e-12f);
                const float r = fmaxf(LGG - dist, 0.f);
                loss += logf(r*r + 1.f);
                nv += 1.f;
            }
        }
    }
    #pragma unroll
    for (int o = 8; o; o >>= 1) { loss += __shfl_xor(loss, o); nv += __shfl_xor(nv, o); }
    if (i == 0) {
        const float v = (__popc(pres) >= 2) ? 1.f : 0.f;
        sl[b] = v * (loss / fmaxf(nv, 1.f));
        sn[b] = v;
    }
    __syncthreads();
    if (tid == 0) {
        float tl = 0.f, tv = 0.f;
        for (int bb = 0; bb < NB; ++bb) { tl += sl[bb]; tv += sn[bb]; }
        out[0] = (tv > 0.f) ? tl / tv : 0.f;
    }
}

extern "C" void kernel_launch(void* const* d_in, const int* in_sizes, int n_in,
                              void* d_out, int out_size, void* d_ws, size_t ws_size,
                              hipStream_t stream) {
    const int*   gk   = (const int*)d_in[0];
    const int*   mask = (const int*)d_in[1];
    const float* sim  = (const float*)d_in[2];
    float* out = (float*)d_out;

    float*    g_sums = (float*)d_ws;                       // NB*NT*NC
    float*    g_cnt  = g_sums + NB*NT*NC;                  // NB*NT
    unsigned* g_pb   = (unsigned*)(g_cnt + NB*NT);         // NB

    const int nws = NB*NT*NC + NB*NT + NB;
    init_ws<<<(nws + 255)/256, 256, 0, stream>>>((float*)d_ws);
    accum<<<NB*BPS*NQ, THREADS, 0, stream>>>(gk, mask, sim, g_sums, g_cnt, g_pb);
    finalize<<<1, 256, 0, stream>>>(g_sums, g_cnt, g_pb, out);
}

// Round 6
// 56.861 us; speedup vs baseline: 4.3368x; 1.0085x over previous
//
#include <hip/hip_runtime.h>

#define NB 16
#define NC 8
#define HW (512*512)
#define NT 16                          // tags 1..16 (tag 0 never participates)
#define BPS 16                         // block-slices per sample
#define THREADS 256
#define PIXB (HW / BPS)                // 16384 pixels per slice
#define ITERS (PIXB / (THREADS*4))     // 16 iters of 4 px/thread
#define NQ 5                           // 4 sim channel-pair quarters + 1 count flavor
#define LGG 3.0f

// ws layout (no init needed -- every slot fully written each run):
//   p_sums [NB][BPS][4][32] f32   quarter partials (f = (c&1)*16 + t, c = 2q+(f>>4))
//   p_cnt  [NB][BPS][16]    f32   count partials
//   p_pb   [NB][BPS]        u32   presence bitmask partials
#define PS_OFF 0
#define PC_OFF (NB*BPS*4*32)
#define PB_OFF (PC_OFF + NB*BPS*16)

// Grid = NB*BPS*NQ = 1280 blocks = exactly 5 blocks/CU (20 waves) -> no
// residency-quantization tail (R5: 2560 blocks = 10/CU ran as 8+2 rounds).
__global__ __launch_bounds__(THREADS) void accum(
    const int* __restrict__ gk, const int* __restrict__ mask,
    const float* __restrict__ sim, float* __restrict__ ws)
{
    const int tid = threadIdx.x;
    const int q   = blockIdx.x % NQ;
    const int bb  = blockIdx.x / NQ;
    const int b   = bb / BPS;
    const int blk = bb % BPS;
    const int base = blk * PIXB;
    const int* gkb = gk + (size_t)b * HW + base;

    __shared__ float    lred[4][2*NT];
    __shared__ unsigned lpb[4];
    const int wid = tid >> 6, lane = tid & 63;

    if (q < 4) {
        const float* sb = sim + (size_t)b*NC*HW + (size_t)(q*2)*HW + base;
        float s0[NT], s1[NT];
        #pragma unroll
        for (int t = 0; t < NT; ++t) { s0[t] = 0.f; s1[t] = 0.f; }

        #pragma unroll 1
        for (int it = 0; it < ITERS; ++it) {
            const int off = (it*THREADS + tid) * 4;
            const int4   g4 = *(const int4*)(gkb + off);
            const float4 v0 = *(const float4*)(sb + off);
            const float4 v1 = *(const float4*)(sb + HW + off);
            const int   gs[4] = {g4.x, g4.y, g4.z, g4.w};
            const float a0[4] = {v0.x, v0.y, v0.z, v0.w};
            const float a1[4] = {v1.x, v1.y, v1.z, v1.w};
            #pragma unroll
            for (int p = 0; p < 4; ++p) {
                const int g = gs[p];
                #pragma unroll
                for (int t = 0; t < NT; ++t) {
                    const float oh = (g == t+1) ? 1.f : 0.f;
                    s0[t] = fmaf(oh, a0[p], s0[t]);
                    s1[t] = fmaf(oh, a1[p], s1[t]);
                }
            }
        }

        #pragma unroll
        for (int t = 0; t < NT; ++t) {
            float x = s0[t], y = s1[t];
            #pragma unroll
            for (int o = 32; o; o >>= 1) { x += __shfl_xor(x, o); y += __shfl_xor(y, o); }
            if (lane == 0) { lred[wid][t] = x; lred[wid][NT + t] = y; }
        }
        __syncthreads();
        if (tid < 2*NT) {
            const float tot = lred[0][tid] + lred[1][tid] + lred[2][tid] + lred[3][tid];
            ws[PS_OFF + (((b*BPS + blk)*4) + q)*32 + tid] = tot;
        }
    } else {
        const int* mb = mask + (size_t)b * HW + base;
        unsigned cnt[NT];
        unsigned pb = 0u;
        #pragma unroll
        for (int t = 0; t < NT; ++t) cnt[t] = 0u;

        #pragma unroll 1
        for (int it = 0; it < ITERS; ++it) {
            const int off = (it*THREADS + tid) * 4;
            const int4 g4 = *(const int4*)(gkb + off);
            const int4 m4 = *(const int4*)(mb  + off);
            const int gs[4] = {g4.x, g4.y, g4.z, g4.w};
            const int ms[4] = {m4.x, m4.y, m4.z, m4.w};
            #pragma unroll
            for (int p = 0; p < 4; ++p) {
                const int g = gs[p];
                pb |= ms[p] ? (1u << g) : 0u;
                #pragma unroll
                for (int t = 0; t < NT; ++t) cnt[t] += (g == t+1) ? 1u : 0u;
            }
        }

        #pragma unroll
        for (int t = 0; t < NT; ++t) {
            unsigned x = cnt[t];
            #pragma unroll
            for (int o = 32; o; o >>= 1) x += __shfl_xor(x, o);
            if (lane == 0) lred[wid][t] = (float)x;
        }
        {
            unsigned u = pb;
            #pragma unroll
            for (int o = 32; o; o >>= 1) u |= __shfl_xor(u, o);
            if (lane == 0) lpb[wid] = u;
        }
        __syncthreads();
        if (tid < NT) {
            const float tot = lred[0][tid] + lred[1][tid] + lred[2][tid] + lred[3][tid];
            ws[PC_OFF + (b*BPS + blk)*NT + tid] = tot;
        }
        if (tid == 0)
            ((unsigned*)ws)[PB_OFF + b*BPS + blk] = lpb[0] | lpb[1] | lpb[2] | lpb[3];
    }
}

__global__ __launch_bounds__(256) void finalize(
    const float* __restrict__ ws, float* __restrict__ out)
{
    __shared__ float    means[NB][NT][NC];
    __shared__ float    cnts[NB][NT];
    __shared__ unsigned pres[NB];
    __shared__ float    sl[NB], sn[NB];
    const int tid = threadIdx.x;

    // counts: thread (b,t) sums 16 slice partials
    {
        const int b = tid >> 4, t = tid & 15;
        float c = 0.f;
        #pragma unroll
        for (int s = 0; s < BPS; ++s) c += ws[PC_OFF + (b*BPS + s)*NT + t];
        cnts[b][t] = c;
    }
    // presence: thread b ORs 16 slice bitmasks
    if (tid < NB) {
        unsigned u = 0u;
        #pragma unroll
        for (int s = 0; s < BPS; ++s) u |= ((const unsigned*)ws)[PB_OFF + tid*BPS + s];
        pres[tid] = u & 0x1FFFEu;      // exclude tag 0
    }
    __syncthreads();

    // means: 2048 (b,t,c) combos, 8 per thread
    #pragma unroll
    for (int k = 0; k < (NB*NT*NC)/256; ++k) {
        const int idx = k*256 + tid;
        const int b = idx >> 7, t = (idx >> 3) & 15, c = idx & 7;
        const int qq = c >> 1, f = (c & 1)*16 + t;
        float s = 0.f;
        #pragma unroll
        for (int sl2 = 0; sl2 < BPS; ++sl2)
            s += ws[PS_OFF + (((b*BPS + sl2)*4) + qq)*32 + f];
        means[b][t][c] = s / fmaxf(cnts[b][t], 1.f);
    }
    __syncthreads();

    const int b = tid >> 4, i = tid & 15;          // sample, tag-1
    const unsigned pr = pres[b];
    float loss = 0.f, nv = 0.f;
    if ((pr >> (i+1)) & 1u) {
        #pragma unroll
        for (int j = 0; j < NT; ++j) {
            if (j != i && ((pr >> (j+1)) & 1u)) {
                float d2 = 0.f;
                #pragma unroll
                for (int c = 0; c < NC; ++c) {
                    const float d = means[b][i][c] - means[b][j][c];
                    d2 += d * d;
                }
                const float dist = sqrtf(d2 + 1e-12f);
                const float r = fmaxf(LGG - dist, 0.f);
                loss += logf(r*r + 1.f);
                nv += 1.f;
            }
        }
    }
    #pragma unroll
    for (int o = 8; o; o >>= 1) { loss += __shfl_xor(loss, o); nv += __shfl_xor(nv, o); }
    if (i == 0) {
        const float v = (__popc(pr) >= 2) ? 1.f : 0.f;
        sl[b] = v * (loss / fmaxf(nv, 1.f));
        sn[b] = v;
    }
    __syncthreads();
    if (tid == 0) {
        float tl = 0.f, tv = 0.f;
        for (int bb = 0; bb < NB; ++bb) { tl += sl[bb]; tv += sn[bb]; }
        out[0] = (tv > 0.f) ? tl / tv : 0.f;
    }
}

extern "C" void kernel_launch(void* const* d_in, const int* in_sizes, int n_in,
                              void* d_out, int out_size, void* d_ws, size_t ws_size,
                              hipStream_t stream) {
    const int*   gk   = (const int*)d_in[0];
    const int*   mask = (const int*)d_in[1];
    const float* sim  = (const float*)d_in[2];
    float* out = (float*)d_out;
    float* ws  = (float*)d_ws;

    accum<<<NB*BPS*NQ, THREADS, 0, stream>>>(gk, mask, sim, ws);
    finalize<<<1, 256, 0, stream>>>(ws, out);
}

// Round 7
// 55.440 us; speedup vs baseline: 4.4479x; 1.0256x over previous
//
#include <hip/hip_runtime.h>

#define NB 16
#define NC 8
#define HW (512*512)
#define NT 16                 // tags 1..16 (tag 0 never participates)
#define LGG 3.0f

#define BLOCKS 2048           // 8 blocks/CU exactly (256 CU)
#define THREADS 256
#define BPSAMP (BLOCKS/NB)    // 128 blocks per sample
#define PXB (HW/BPSAMP)       // 2048 pixels per block
#define PXW (PXB/4)           // 512 pixels per wave
#define NMFMA (PXW/32)        // 16 MFMAs per wave

typedef __attribute__((ext_vector_type(8))) short bf16x8;
typedef __attribute__((ext_vector_type(4))) float f32x4;

// ws layout (fully overwritten every run -- no init kernel needed):
//   psum [BLOCKS][144] f32   per-block S[t][c] partials (c=0..7 ch, c=8 count)
//   ppb  [BLOCKS]      u32   per-block presence bitmask
//   sout [32]          f32   per-sample loss[16] + valid[16]

__device__ __forceinline__ unsigned pk_bf16(float x, float y) {
    unsigned r;
    asm("v_cvt_pk_bf16_f32 %0, %1, %2" : "=v"(r) : "v"(x), "v"(y));
    return r;   // lo = bf16(x), hi = bf16(y), RNE
}

__global__ __launch_bounds__(THREADS) void accum(
    const int* __restrict__ gk, const int* __restrict__ mask,
    const float* __restrict__ sim,
    float* __restrict__ psum, unsigned* __restrict__ ppb)
{
    const int tid  = threadIdx.x;
    const int lane = tid & 63, wid = tid >> 6;
    const int bid  = blockIdx.x;
    const int b    = bid / BPSAMP;          // sample
    const int sb   = bid % BPSAMP;          // block within sample
    const int c    = lane & 15;             // D column role: 0..7 ch, 8 ones, 9 mask
    const int l4   = lane >> 4;             // k-chunk 0..3 (8 pixels each)
    const int p0   = sb * PXB + wid * PXW + l4 * 8;

    const int*   gkp = gk   + (size_t)b * HW + p0;
    const int*   mkp = mask + (size_t)b * HW + p0;
    const float* sp  = sim  + ((size_t)b * NC + c) * HW + p0;  // only deref'd if c<8

    __shared__ float    lred[4][256];
    __shared__ unsigned s_pb;
    if (tid == 0) s_pb = 0u;
    __syncthreads();

    f32x4 acc = {0.f, 0.f, 0.f, 0.f};
    unsigned pb = 0u;
    const int r1 = c + 1;                   // this lane's A-row = tag r1

    #pragma unroll 1
    for (int it = 0; it < NMFMA; ++it) {
        const int off = it * 32;            // 32 pixels per MFMA
        const int4 g0 = *(const int4*)(gkp + off);
        const int4 g1 = *(const int4*)(gkp + off + 4);

        // A fragment: one-hot bf16 (exact). slot (lane,j) -> pixel p0+off+j.
        union { bf16x8 v; unsigned u[4]; } A;
        A.u[0] = (g0.x == r1 ? 0x3F80u : 0u) | (g0.y == r1 ? 0x3F800000u : 0u);
        A.u[1] = (g0.z == r1 ? 0x3F80u : 0u) | (g0.w == r1 ? 0x3F800000u : 0u);
        A.u[2] = (g1.x == r1 ? 0x3F80u : 0u) | (g1.y == r1 ? 0x3F800000u : 0u);
        A.u[3] = (g1.z == r1 ? 0x3F80u : 0u) | (g1.w == r1 ? 0x3F800000u : 0u);

        // B fragment: sim channel c (bf16 RNE), ones column at c==8, else 0.
        union { bf16x8 v; unsigned u[4]; } B;
        if (c < 8) {
            const float4 v0 = *(const float4*)(sp + off);
            const float4 v1 = *(const float4*)(sp + off + 4);
            B.u[0] = pk_bf16(v0.x, v0.y); B.u[1] = pk_bf16(v0.z, v0.w);
            B.u[2] = pk_bf16(v1.x, v1.y); B.u[3] = pk_bf16(v1.z, v1.w);
        } else if (c == 8) {
            B.u[0] = B.u[1] = B.u[2] = B.u[3] = 0x3F803F80u;  // bf16 1.0 pair
        } else {
            B.u[0] = B.u[1] = B.u[2] = B.u[3] = 0u;
            if (c == 9) {                   // presence duty on 4 lanes
                const int4 m0 = *(const int4*)(mkp + off);
                const int4 m1 = *(const int4*)(mkp + off + 4);
                if (m0.x) pb |= 1u << g0.x;
                if (m0.y) pb |= 1u << g0.y;
                if (m0.z) pb |= 1u << g0.z;
                if (m0.w) pb |= 1u << g0.w;
                if (m1.x) pb |= 1u << g1.x;
                if (m1.y) pb |= 1u << g1.y;
                if (m1.z) pb |= 1u << g1.z;
                if (m1.w) pb |= 1u << g1.w;
            }
        }

        acc = __builtin_amdgcn_mfma_f32_16x16x32_bf16(A.v, B.v, acc, 0, 0, 0);
    }

    // D layout: col = lane&15, row = (lane>>4)*4 + reg
    const int row0 = (lane >> 4) * 4;
    #pragma unroll
    for (int i = 0; i < 4; ++i) lred[wid][(row0 + i) * 16 + c] = acc[i];
    if (c == 9) atomicOr(&s_pb, pb);
    __syncthreads();

    if (tid < NT * 9) {                     // 144: r = tid/9 tag-row, cc = tid%9
        const int r = tid / 9, cc = tid % 9;
        const float s = lred[0][r*16+cc] + lred[1][r*16+cc]
                      + lred[2][r*16+cc] + lred[3][r*16+cc];
        psum[(size_t)bid * 144 + tid] = s;
    }
    if (tid == 0) ppb[bid] = s_pb;
}

__global__ __launch_bounds__(256) void reduce_sample(
    const float* __restrict__ psum, const unsigned* __restrict__ ppb,
    float* __restrict__ sout)
{
    const int b = blockIdx.x, tid = threadIdx.x;
    __shared__ float    S[144];
    __shared__ float    cnts[NT];
    __shared__ float    means[NT][NC];
    __shared__ unsigned s_pres;
    __shared__ float    lsum[4], lnv[4];
    if (tid == 0) s_pres = 0u;
    __syncthreads();

    if (tid < 144) {
        float s = 0.f;
        for (int i = 0; i < BPSAMP; ++i)
            s += psum[(size_t)(b * BPSAMP + i) * 144 + tid];
        S[tid] = s;
    }
    {
        unsigned u = (tid < BPSAMP) ? ppb[b * BPSAMP + tid] : 0u;
        #pragma unroll
        for (int o = 32; o; o >>= 1) u |= __shfl_xor(u, o);
        if ((tid & 63) == 0) atomicOr(&s_pres, u);
    }
    __syncthreads();
    if (tid < NT) cnts[tid] = S[tid * 9 + 8];
    __syncthreads();
    if (tid < NT * NC)
        means[tid >> 3][tid & 7] = S[(tid >> 3) * 9 + (tid & 7)]
                                   / fmaxf(cnts[tid >> 3], 1.f);
    __syncthreads();

    const unsigned pres = s_pres & 0x1FFFEu;       // drop tag 0
    const int i = tid >> 4, j = tid & 15;
    float loss = 0.f, nv = 0.f;
    if (i != j && ((pres >> (i + 1)) & 1u) && ((pres >> (j + 1)) & 1u)) {
        float d2 = 0.f;
        #pragma unroll
        for (int cc = 0; cc < NC; ++cc) {
            const float d = means[i][cc] - means[j][cc];
            d2 += d * d;
        }
        const float dist = sqrtf(d2 + 1e-12f);
        const float r = fmaxf(LGG - dist, 0.f);
        loss = logf(r * r + 1.f);
        nv = 1.f;
    }
    #pragma unroll
    for (int o = 32; o; o >>= 1) { loss += __shfl_xor(loss, o); nv += __shfl_xor(nv, o); }
    if ((tid & 63) == 0) { lsum[tid >> 6] = loss; lnv[tid >> 6] = nv; }
    __syncthreads();
    if (tid == 0) {
        const float tl = lsum[0] + lsum[1] + lsum[2] + lsum[3];
        const float tn = lnv[0] + lnv[1] + lnv[2] + lnv[3];
        const float v = (__popc(pres) >= 2) ? 1.f : 0.f;
        sout[b]      = v * (tl / fmaxf(tn, 1.f));
        sout[NB + b] = v;
    }
}

__global__ __launch_bounds__(64) void final_k(
    const float* __restrict__ sout, float* __restrict__ out)
{
    const int tid = threadIdx.x;
    float l = (tid < NB) ? sout[tid]      : 0.f;
    float v = (tid < NB) ? sout[NB + tid] : 0.f;
    #pragma unroll
    for (int o = 32; o; o >>= 1) { l += __shfl_xor(l, o); v += __shfl_xor(v, o); }
    if (tid == 0) out[0] = (v > 0.f) ? l / v : 0.f;
}

extern "C" void kernel_launch(void* const* d_in, const int* in_sizes, int n_in,
                              void* d_out, int out_size, void* d_ws, size_t ws_size,
                              hipStream_t stream) {
    const int*   gk   = (const int*)d_in[0];
    const int*   mask = (const int*)d_in[1];
    const float* sim  = (const float*)d_in[2];
    float* out = (float*)d_out;

    float*    psum = (float*)d_ws;                         // BLOCKS*144
    unsigned* ppb  = (unsigned*)(psum + BLOCKS * 144);     // BLOCKS
    float*    sout = (float*)(ppb + BLOCKS);               // 32

    accum<<<BLOCKS, THREADS, 0, stream>>>(gk, mask, sim, psum, ppb);
    reduce_sample<<<NB, 256, 0, stream>>>(psum, ppb, sout);
    final_k<<<1, 64, 0, stream>>>(sout, out);
}

// Round 8
// 54.712 us; speedup vs baseline: 4.5071x; 1.0133x over previous
//
#include <hip/hip_runtime.h>

#define NB 16
#define NC 8
#define HW (512*512)
#define NT 16                 // tags 1..16 (tag 0 never participates)
#define LGG 3.0f

#define BLOCKS 2048           // 8 blocks/CU exactly (256 CU)
#define THREADS 256
#define BPSAMP (BLOCKS/NB)    // 128 blocks per sample
#define PXB (HW/BPSAMP)       // 2048 pixels per block
#define PXW (PXB/4)           // 512 pixels per wave
#define NMFMA (PXW/32)        // 16 MFMAs per wave
#define NCOL 10               // D cols: 0..7 = channel sums, 8 = count, 9 = masked count
#define ACCW (NT*NCOL)        // 160 floats per sample

typedef __attribute__((ext_vector_type(8))) short bf16x8;
typedef __attribute__((ext_vector_type(4))) float f32x4;

// ws layout: g_acc [NB][160] f32 (zeroed by init_ws each call; atomicAdd'd by accum)

__device__ __forceinline__ unsigned pk_bf16(float x, float y) {
    unsigned r;
    asm("v_cvt_pk_bf16_f32 %0, %1, %2" : "=v"(r) : "v"(x), "v"(y));
    return r;   // lo = bf16(x), hi = bf16(y), RNE
}

__global__ __launch_bounds__(256) void init_ws(float* g_acc) {
    const int i = threadIdx.x;
    #pragma unroll
    for (int k = 0; k < NB*ACCW; k += 256)
        if (k + i < NB*ACCW) g_acc[k + i] = 0.f;
}

__global__ __launch_bounds__(THREADS) void accum(
    const int* __restrict__ gk, const int* __restrict__ mask,
    const float* __restrict__ sim, float* __restrict__ g_acc)
{
    const int tid  = threadIdx.x;
    const int lane = tid & 63, wid = tid >> 6;
    const int bid  = blockIdx.x;
    const int b    = bid / BPSAMP;          // sample
    const int sb   = bid % BPSAMP;          // block within sample
    const int c    = lane & 15;             // D column role: 0..7 ch, 8 ones, 9 mask
    const int l4   = lane >> 4;             // k-chunk 0..3 (8 pixels each)
    const int p0   = sb * PXB + wid * PXW + l4 * 8;

    const int*   gkp = gk   + (size_t)b * HW + p0;
    const int*   mkp = mask + (size_t)b * HW + p0;
    const float* sp  = sim  + ((size_t)b * NC + c) * HW + p0;  // deref'd only if c<8

    __shared__ float lred[4][256];

    f32x4 acc = {0.f, 0.f, 0.f, 0.f};
    const int r1 = c + 1;                   // this lane's one-hot tag

    #pragma unroll 2
    for (int it = 0; it < NMFMA; ++it) {
        const int off = it * 32;            // 32 pixels per MFMA
        const int4 g0 = *(const int4*)(gkp + off);
        const int4 g1 = *(const int4*)(gkp + off + 4);

        // A fragment: one-hot bf16 (exact). slot (lane,j) -> pixel p0+off+j.
        union { bf16x8 v; unsigned u[4]; } A;
        A.u[0] = (g0.x == r1 ? 0x3F80u : 0u) | (g0.y == r1 ? 0x3F800000u : 0u);
        A.u[1] = (g0.z == r1 ? 0x3F80u : 0u) | (g0.w == r1 ? 0x3F800000u : 0u);
        A.u[2] = (g1.x == r1 ? 0x3F80u : 0u) | (g1.y == r1 ? 0x3F800000u : 0u);
        A.u[3] = (g1.z == r1 ? 0x3F80u : 0u) | (g1.w == r1 ? 0x3F800000u : 0u);

        // B fragment by column: sim channel (c<8), ones (c==8: counts),
        // mask 0/1 (c==9: masked counts -> presence), zero otherwise.
        union { bf16x8 v; unsigned u[4]; } B;
        if (c < 8) {
            const float4 v0 = *(const float4*)(sp + off);
            const float4 v1 = *(const float4*)(sp + off + 4);
            B.u[0] = pk_bf16(v0.x, v0.y); B.u[1] = pk_bf16(v0.z, v0.w);
            B.u[2] = pk_bf16(v1.x, v1.y); B.u[3] = pk_bf16(v1.z, v1.w);
        } else if (c == 8) {
            B.u[0] = B.u[1] = B.u[2] = B.u[3] = 0x3F803F80u;  // bf16 1.0 pair
        } else if (c == 9) {
            const int4 m0 = *(const int4*)(mkp + off);
            const int4 m1 = *(const int4*)(mkp + off + 4);
            B.u[0] = (m0.x ? 0x3F80u : 0u) | (m0.y ? 0x3F800000u : 0u);
            B.u[1] = (m0.z ? 0x3F80u : 0u) | (m0.w ? 0x3F800000u : 0u);
            B.u[2] = (m1.x ? 0x3F80u : 0u) | (m1.y ? 0x3F800000u : 0u);
            B.u[3] = (m1.z ? 0x3F80u : 0u) | (m1.w ? 0x3F800000u : 0u);
        } else {
            B.u[0] = B.u[1] = B.u[2] = B.u[3] = 0u;
        }

        acc = __builtin_amdgcn_mfma_f32_16x16x32_bf16(A.v, B.v, acc, 0, 0, 0);
    }

    // D layout: col = lane&15, row = (lane>>4)*4 + reg  (verified R7, absmax 0)
    const int row0 = (lane >> 4) * 4;
    #pragma unroll
    for (int i = 0; i < 4; ++i) lred[wid][(row0 + i) * 16 + c] = acc[i];
    __syncthreads();

    if (tid < NT * NCOL) {                  // 160: r = tag row, cc = column
        const int r = tid / NCOL, cc = tid % NCOL;
        const float s = lred[0][r*16+cc] + lred[1][r*16+cc]
                      + lred[2][r*16+cc] + lred[3][r*16+cc];
        atomicAdd(&g_acc[b * ACCW + tid], s);
    }
}

__global__ __launch_bounds__(256) void finalize(
    const float* __restrict__ g_acc, float* __restrict__ out)
{
    __shared__ float    means[NB][NT][NC];
    __shared__ unsigned pres[NB];
    __shared__ float    sl[NB], sn[NB];
    const int tid = threadIdx.x;

    if (tid < NB) pres[tid] = 0u;
    __syncthreads();

    // one thread per (sample, tag): means + presence
    {
        const int b = tid >> 4, t = tid & 15;
        const float* row = g_acc + b * ACCW + t * NCOL;
        const float cnt = row[8];
        const float mc  = row[9];
        const float inv = 1.f / fmaxf(cnt, 1.f);
        #pragma unroll
        for (int cc = 0; cc < NC; ++cc) means[b][t][cc] = row[cc] * inv;
        if (mc > 0.5f) atomicOr(&pres[b], 1u << (t + 1));
    }
    __syncthreads();

    const int b = tid >> 4, i = tid & 15;          // sample, tag-1
    const unsigned pr = pres[b];                    // bits 1..16
    float loss = 0.f, nv = 0.f;
    if ((pr >> (i + 1)) & 1u) {
        #pragma unroll
        for (int j = 0; j < NT; ++j) {
            if (j != i && ((pr >> (j + 1)) & 1u)) {
                float d2 = 0.f;
                #pragma unroll
                for (int cc = 0; cc < NC; ++cc) {
                    const float d = means[b][i][cc] - means[b][j][cc];
                    d2 += d * d;
                }
                const float dist = sqrtf(d2 + 1e-12f);
                const float r = fmaxf(LGG - dist, 0.f);
                loss += logf(r * r + 1.f);
                nv += 1.f;
            }
        }
    }
    #pragma unroll
    for (int o = 8; o; o >>= 1) { loss += __shfl_xor(loss, o); nv += __shfl_xor(nv, o); }
    if (i == 0) {
        const float v = (__popc(pr) >= 2) ? 1.f : 0.f;
        sl[b] = v * (loss / fmaxf(nv, 1.f));
        sn[b] = v;
    }
    __syncthreads();
    if (tid == 0) {
        float tl = 0.f, tv = 0.f;
        for (int bb = 0; bb < NB; ++bb) { tl += sl[bb]; tv += sn[bb]; }
        out[0] = (tv > 0.f) ? tl / tv : 0.f;
    }
}

extern "C" void kernel_launch(void* const* d_in, const int* in_sizes, int n_in,
                              void* d_out, int out_size, void* d_ws, size_t ws_size,
                              hipStream_t stream) {
    const int*   gk   = (const int*)d_in[0];
    const int*   mask = (const int*)d_in[1];
    const float* sim  = (const float*)d_in[2];
    float* out   = (float*)d_out;
    float* g_acc = (float*)d_ws;      // NB*160 floats

    init_ws<<<1, 256, 0, stream>>>(g_acc);
    accum<<<BLOCKS, THREADS, 0, stream>>>(gk, mask, sim, g_acc);
    finalize<<<1, 256, 0, stream>>>(g_acc, out);
}